// Round 2
// baseline (5970.543 us; speedup 1.0000x reference)
//
#include <hip/hip_runtime.h>
#include <cstddef>
#include <cstdint>

// Problem constants
constexpr int cB = 8, cH = 8, cN = 4096, cD = 64, cM = 64, cL = 64;

// ---------------------------------------------------------------------------
// K1: landmarks  q_l/k_l[bh][m][d] = mean over l=64 tokens
// ---------------------------------------------------------------------------
__global__ void k_landmarks(const float* __restrict__ q, const float* __restrict__ k,
                            float* __restrict__ ql, float* __restrict__ kl) {
  int bm = blockIdx.x;          // BH*M = 4096
  int bh = bm >> 6, m = bm & 63;
  int d = threadIdx.x;          // 64
  size_t base = ((size_t)bh * cN + (size_t)m * cL) * cD + d;
  float sq = 0.f, sk = 0.f;
  for (int t = 0; t < cL; ++t) {
    sq += q[base + (size_t)t * cD];
    sk += k[base + (size_t)t * cD];
  }
  size_t ob = ((size_t)bh * cM + m) * cD + d;
  ql[ob] = sq * (1.0f / cL);
  kl[ob] = sk * (1.0f / cL);
}

// ---------------------------------------------------------------------------
// K2: sim2 = q_l k_l^T, mix heads (Wsim2), softmax rows, write attn2.
// Also atomicMax of global col-sum max (scal[0]) and row-sum max (scal[1]).
// ---------------------------------------------------------------------------
__global__ void __launch_bounds__(256) k_sim2(const float* __restrict__ ql,
                                              const float* __restrict__ kl,
                                              const float* __restrict__ Wsim2,
                                              float* __restrict__ attn2,
                                              unsigned int* __restrict__ scal) {
  __shared__ float qs[64][65];
  __shared__ float ks[64][65];
  __shared__ float acc[64 * 65];
  int b = blockIdx.x >> 3, kk = blockIdx.x & 7;
  int tid = threadIdx.x;
  for (int idx = tid; idx < 64 * 64; idx += 256)
    acc[(idx >> 6) * 65 + (idx & 63)] = 0.f;
  int ri = (tid >> 4) * 4, ci = (tid & 15) * 4;
  for (int h = 0; h < 8; ++h) {
    __syncthreads();
    const float* qg = ql + (size_t)(b * 8 + h) * 4096;
    const float* kg = kl + (size_t)(b * 8 + h) * 4096;
    for (int idx = tid; idx < 4096; idx += 256) {
      qs[idx >> 6][idx & 63] = qg[idx];
      ks[idx >> 6][idx & 63] = kg[idx];
    }
    __syncthreads();
    float w = Wsim2[h * 8 + kk];
    float s[4][4] = {};
    for (int d = 0; d < 64; ++d) {
      float a0 = qs[ri][d], a1 = qs[ri + 1][d], a2 = qs[ri + 2][d], a3 = qs[ri + 3][d];
      float b0 = ks[ci][d], b1 = ks[ci + 1][d], b2 = ks[ci + 2][d], b3 = ks[ci + 3][d];
      s[0][0] += a0 * b0; s[0][1] += a0 * b1; s[0][2] += a0 * b2; s[0][3] += a0 * b3;
      s[1][0] += a1 * b0; s[1][1] += a1 * b1; s[1][2] += a1 * b2; s[1][3] += a1 * b3;
      s[2][0] += a2 * b0; s[2][1] += a2 * b1; s[2][2] += a2 * b2; s[2][3] += a2 * b3;
      s[3][0] += a3 * b0; s[3][1] += a3 * b1; s[3][2] += a3 * b2; s[3][3] += a3 * b3;
    }
    #pragma unroll
    for (int x = 0; x < 4; ++x)
      #pragma unroll
      for (int y = 0; y < 4; ++y)
        acc[(ri + x) * 65 + ci + y] += w * s[x][y];
  }
  __syncthreads();
  if (tid < 64) {
    float mx = -1e30f;
    for (int j = 0; j < 64; ++j) mx = fmaxf(mx, acc[tid * 65 + j]);
    float s = 0.f;
    for (int j = 0; j < 64; ++j) {
      float e = expf(acc[tid * 65 + j] - mx);
      acc[tid * 65 + j] = e;
      s += e;
    }
    float inv = 1.0f / s;
    float rs = 0.f;
    for (int j = 0; j < 64; ++j) {
      float p = acc[tid * 65 + j] * inv;
      acc[tid * 65 + j] = p;
      rs += p;
    }
    atomicMax(scal + 1, __float_as_uint(rs));
  }
  __syncthreads();
  if (tid < 64) {
    float cs = 0.f;
    for (int i = 0; i < 64; ++i) cs += acc[i * 65 + tid];
    atomicMax(scal + 0, __float_as_uint(cs));
  }
  __syncthreads();
  float* op = attn2 + (size_t)(b * 8 + kk) * 4096;
  for (int idx = tid; idx < 4096; idx += 256)
    op[idx] = acc[(idx >> 6) * 65 + (idx & 63)];
}

// ---------------------------------------------------------------------------
// K3: Moore-Penrose pinv, 6 Newton-Schulz iterations in LDS, per (b,k) block.
// ---------------------------------------------------------------------------
__device__ __forceinline__ void mm64(float* __restrict__ Dst, const float* S,
                                     float c0, float c1, const float* __restrict__ P,
                                     const float* __restrict__ Q, int tid) {
  int ri = (tid >> 4) * 4, ci = (tid & 15) * 4;
  float s[4][4] = {};
  for (int k = 0; k < 64; ++k) {
    float a0 = P[(ri + 0) * 65 + k], a1 = P[(ri + 1) * 65 + k];
    float a2 = P[(ri + 2) * 65 + k], a3 = P[(ri + 3) * 65 + k];
    float b0 = Q[k * 65 + ci + 0], b1 = Q[k * 65 + ci + 1];
    float b2 = Q[k * 65 + ci + 2], b3 = Q[k * 65 + ci + 3];
    s[0][0] += a0 * b0; s[0][1] += a0 * b1; s[0][2] += a0 * b2; s[0][3] += a0 * b3;
    s[1][0] += a1 * b0; s[1][1] += a1 * b1; s[1][2] += a1 * b2; s[1][3] += a1 * b3;
    s[2][0] += a2 * b0; s[2][1] += a2 * b1; s[2][2] += a2 * b2; s[2][3] += a2 * b3;
    s[3][0] += a3 * b0; s[3][1] += a3 * b1; s[3][2] += a3 * b2; s[3][3] += a3 * b3;
  }
  #pragma unroll
  for (int x = 0; x < 4; ++x)
    #pragma unroll
    for (int y = 0; y < 4; ++y) {
      float r = c1 * s[x][y];
      if (S) r += c0 * S[(ri + x) * 65 + ci + y];
      Dst[(ri + x) * 65 + ci + y] = r;
    }
}

__global__ void __launch_bounds__(256) k_pinv(const float* __restrict__ attn2,
                                              float* __restrict__ attn2inv,
                                              const unsigned int* __restrict__ scal) {
  __shared__ float bufs[5][64 * 65];
  float* X = bufs[0];
  float* Z = bufs[1];
  float* T1 = bufs[2];
  float* T2 = bufs[3];
  float* T3 = bufs[4];
  int tid = threadIdx.x;
  const float* xg = attn2 + (size_t)blockIdx.x * 4096;
  for (int idx = tid; idx < 4096; idx += 256)
    X[(idx >> 6) * 65 + (idx & 63)] = xg[idx];
  float denom = __uint_as_float(scal[0]) * __uint_as_float(scal[1]);
  float invd = 1.0f / denom;
  __syncthreads();
  for (int idx = tid; idx < 4096; idx += 256) {
    int i = idx >> 6, j = idx & 63;
    Z[i * 65 + j] = X[j * 65 + i] * invd;
  }
  __syncthreads();
  for (int it = 0; it < 6; ++it) {
    mm64(T1, nullptr, 0.f, 1.f, X, Z, tid);          __syncthreads();
    mm64(T2, T1, 7.f, -1.f, T1, T1, tid);            __syncthreads();
    mm64(T3, T1, 15.f, -1.f, T1, T2, tid);           __syncthreads();
    mm64(T2, Z, 13.f * 0.25f, -0.25f, Z, T3, tid);   __syncthreads();
    float* tmp = Z; Z = T2; T2 = tmp;
  }
  float* og = attn2inv + (size_t)blockIdx.x * 4096;
  for (int idx = tid; idx < 4096; idx += 256)
    og[idx] = Z[(idx >> 6) * 65 + (idx & 63)];
}

// ---------------------------------------------------------------------------
// K4: head-mix of 64x64 mats: out[b][k2] = sum_k in[b][k] * W[k][k2]
// ---------------------------------------------------------------------------
__global__ void k_mix_heads64(const float* __restrict__ in, const float* __restrict__ W,
                              float* __restrict__ out) {
  int b = blockIdx.x >> 3, k2 = blockIdx.x & 7;
  int tid = threadIdx.x;
  __shared__ float w[8];
  if (tid < 8) w[tid] = W[tid * 8 + k2];
  __syncthreads();
  const float* ib = in + (size_t)b * 8 * 4096;
  float* ob = out + ((size_t)b * 8 + k2) * 4096;
  for (int idx = tid; idx < 4096; idx += 256) {
    float s = 0.f;
    #pragma unroll
    for (int k = 0; k < 8; ++k) s += ib[(size_t)k * 4096 + idx] * w[k];
    ob[idx] = s;
  }
}

// ---------------------------------------------------------------------------
// K5: sim3m[b][k][i][j] = sum_h Wsim3[h][k]*(q_l[b,h,i,:].k[b,h,j,:])
// Register accumulators (8k x 8j per thread); LDS only for staging.
// Block per (b, j-tile 32): i = tid>>2 (0..63), jb = (tid&3)*8.
// ---------------------------------------------------------------------------
__global__ void __launch_bounds__(256) k_sim3(const float* __restrict__ ql,
                                              const float* __restrict__ kg,
                                              const float* __restrict__ Wsim3,
                                              float* __restrict__ sim3m) {
  __shared__ float qls[64 * 65];   // [i][d] pitch 65
  __shared__ float ksT[64 * 36];   // [d][j] pitch 36 (16B-aligned rows)
  __shared__ float w3[64];
  int b = blockIdx.x >> 7, jt = blockIdx.x & 127;
  int j0 = jt * 32, tid = threadIdx.x;
  if (tid < 64) w3[tid] = Wsim3[tid];
  int i = tid >> 2, jb = (tid & 3) * 8;
  float acc[8][8] = {};
  for (int h = 0; h < 8; ++h) {
    __syncthreads();
    const float* qg = ql + (size_t)(b * 8 + h) * 4096;
    for (int idx = tid; idx < 4096; idx += 256)
      qls[(idx >> 6) * 65 + (idx & 63)] = qg[idx];
    const float* kp = kg + ((size_t)(b * 8 + h) * cN + j0) * 64;
    for (int idx = tid; idx < 2048; idx += 256)
      ksT[(idx & 63) * 36 + (idx >> 6)] = kp[idx];
    __syncthreads();
    float s[8] = {};
    for (int d = 0; d < 64; ++d) {
      float a = qls[i * 65 + d];
      float4 k0 = *(const float4*)&ksT[d * 36 + jb];
      float4 k1 = *(const float4*)&ksT[d * 36 + jb + 4];
      s[0] += a * k0.x; s[1] += a * k0.y; s[2] += a * k0.z; s[3] += a * k0.w;
      s[4] += a * k1.x; s[5] += a * k1.y; s[6] += a * k1.z; s[7] += a * k1.w;
    }
    #pragma unroll
    for (int k = 0; k < 8; ++k) {
      float w = w3[h * 8 + k];
      #pragma unroll
      for (int c = 0; c < 8; ++c) acc[k][c] += w * s[c];
    }
  }
  #pragma unroll
  for (int k = 0; k < 8; ++k) {
    float* op = sim3m + ((size_t)((b * 8 + k) * 64 + i)) * cN + j0 + jb;
    *(float4*)op = make_float4(acc[k][0], acc[k][1], acc[k][2], acc[k][3]);
    *(float4*)(op + 4) = make_float4(acc[k][4], acc[k][5], acc[k][6], acc[k][7]);
  }
}

// ---------------------------------------------------------------------------
// K6: row stats for softmax over j=4096: one block per (b,k,i) row.
// ---------------------------------------------------------------------------
__global__ void k_stats3(const float* __restrict__ sim3m, float* __restrict__ rmax,
                         float* __restrict__ rsum) {
  int row = blockIdx.x; // 4096
  const float* rp = sim3m + (size_t)row * cN;
  int tid = threadIdx.x;
  float vv[16];
  float mx = -1e30f;
  #pragma unroll
  for (int t = 0; t < 16; ++t) {
    vv[t] = rp[tid + t * 256];
    mx = fmaxf(mx, vv[t]);
  }
  __shared__ float red[8];
  for (int off = 32; off > 0; off >>= 1) mx = fmaxf(mx, __shfl_down(mx, off));
  if ((tid & 63) == 0) red[tid >> 6] = mx;
  __syncthreads();
  mx = fmaxf(fmaxf(red[0], red[1]), fmaxf(red[2], red[3]));
  float s = 0.f;
  #pragma unroll
  for (int t = 0; t < 16; ++t) s += expf(vv[t] - mx);
  for (int off = 32; off > 0; off >>= 1) s += __shfl_down(s, off);
  __syncthreads();
  if ((tid & 63) == 0) red[4 + (tid >> 6)] = s;
  __syncthreads();
  if (tid == 0) {
    rmax[row] = mx;
    rsum[row] = red[4] + red[5] + red[6] + red[7];
  }
}

// ---------------------------------------------------------------------------
// K7: in-place softmax + Wattn3 head-mix on sim3m, register-resident.
// One thread per (b,i,j); 8 k-values in registers. 8192 blocks x 256.
// ---------------------------------------------------------------------------
__global__ void __launch_bounds__(256) k_smx3(float* __restrict__ sim3m,
                                              const float* __restrict__ rmax,
                                              const float* __restrict__ rsum,
                                              const float* __restrict__ Wattn3) {
  __shared__ float w[64];
  int tid = threadIdx.x;
  if (tid < 64) w[tid] = Wattn3[tid];
  __syncthreads();
  int gid = blockIdx.x * 256 + tid;   // 2^21 = 8b * 64i * 4096j
  int j = gid & 4095;
  int i = (gid >> 12) & 63;
  int b = gid >> 18;
  float p[8];
  #pragma unroll
  for (int k = 0; k < 8; ++k) {
    int row = (b * 8 + k) * 64 + i;
    p[k] = expf(sim3m[(size_t)row * cN + j] - rmax[row]) / rsum[row];
  }
  #pragma unroll
  for (int k2 = 0; k2 < 8; ++k2) {
    float t = 0.f;
    #pragma unroll
    for (int k = 0; k < 8; ++k) t += p[k] * w[k * 8 + k2];
    int row = (b * 8 + k2) * 64 + i;
    sim3m[(size_t)row * cN + j] = t;
  }
}

// ---------------------------------------------------------------------------
// K8: T3 partials: T3p[c][bh] = attn3f[bh][:, cchunk] @ v[bh][cchunk, :]
// 4 j-chunks of 1024 -> 256 blocks (one per CU).
// ---------------------------------------------------------------------------
__global__ void __launch_bounds__(256) k_t3(const float* __restrict__ attn3f,
                                            const float* __restrict__ v,
                                            float* __restrict__ T3p) {
  __shared__ float As[64][65];
  __shared__ float Vs[64][68];
  int bh = blockIdx.x >> 2, chunk = blockIdx.x & 3;
  int tid = threadIdx.x;
  int ri = (tid >> 4) * 4, ci = (tid & 15) * 4;
  float acc[4][4] = {};
  for (int jt = chunk * 16; jt < chunk * 16 + 16; ++jt) {
    __syncthreads();
    const float* ap = attn3f + (size_t)bh * 64 * cN + jt * 64;
    for (int idx = tid; idx < 4096; idx += 256)
      As[idx >> 6][idx & 63] = ap[(size_t)(idx >> 6) * cN + (idx & 63)];
    const float* vp = v + ((size_t)bh * cN + jt * 64) * 64;
    for (int idx = tid; idx < 4096; idx += 256)
      Vs[idx >> 6][idx & 63] = vp[idx];
    __syncthreads();
    for (int j = 0; j < 64; ++j) {
      float a0 = As[ri][j], a1 = As[ri + 1][j], a2 = As[ri + 2][j], a3 = As[ri + 3][j];
      float b0 = Vs[j][ci], b1 = Vs[j][ci + 1], b2 = Vs[j][ci + 2], b3 = Vs[j][ci + 3];
      acc[0][0] += a0 * b0; acc[0][1] += a0 * b1; acc[0][2] += a0 * b2; acc[0][3] += a0 * b3;
      acc[1][0] += a1 * b0; acc[1][1] += a1 * b1; acc[1][2] += a1 * b2; acc[1][3] += a1 * b3;
      acc[2][0] += a2 * b0; acc[2][1] += a2 * b1; acc[2][2] += a2 * b2; acc[2][3] += a2 * b3;
      acc[3][0] += a3 * b0; acc[3][1] += a3 * b1; acc[3][2] += a3 * b2; acc[3][3] += a3 * b3;
    }
  }
  float* op = T3p + ((size_t)chunk * 64 + bh) * 4096;
  #pragma unroll
  for (int x = 0; x < 4; ++x)
    #pragma unroll
    for (int y = 0; y < 4; ++y)
      op[(ri + x) * 64 + ci + y] = acc[x][y];
}

// ---------------------------------------------------------------------------
// K9: T2[bh] = attn2m[bh] @ (sum of 4 T3 partials). Block per bh.
// ---------------------------------------------------------------------------
__global__ void __launch_bounds__(256) k_t2(const float* __restrict__ attn2m,
                                            const float* __restrict__ T3p,
                                            float* __restrict__ T2) {
  __shared__ float As[64][65];
  __shared__ float Bs[64][68];
  int bh = blockIdx.x, tid = threadIdx.x;
  const float* ap = attn2m + (size_t)bh * 4096;
  for (int idx = tid; idx < 4096; idx += 256) {
    As[idx >> 6][idx & 63] = ap[idx];
    float s = 0.f;
    #pragma unroll
    for (int c = 0; c < 4; ++c) s += T3p[((size_t)c * 64 + bh) * 4096 + idx];
    Bs[idx >> 6][idx & 63] = s;
  }
  __syncthreads();
  int ri = (tid >> 4) * 4, ci = (tid & 15) * 4;
  float acc[4][4] = {};
  for (int j = 0; j < 64; ++j) {
    float a0 = As[ri][j], a1 = As[ri + 1][j], a2 = As[ri + 2][j], a3 = As[ri + 3][j];
    float b0 = Bs[j][ci], b1 = Bs[j][ci + 1], b2 = Bs[j][ci + 2], b3 = Bs[j][ci + 3];
    acc[0][0] += a0 * b0; acc[0][1] += a0 * b1; acc[0][2] += a0 * b2; acc[0][3] += a0 * b3;
    acc[1][0] += a1 * b0; acc[1][1] += a1 * b1; acc[1][2] += a1 * b2; acc[1][3] += a1 * b3;
    acc[2][0] += a2 * b0; acc[2][1] += a2 * b1; acc[2][2] += a2 * b2; acc[2][3] += a2 * b3;
    acc[3][0] += a3 * b0; acc[3][1] += a3 * b1; acc[3][2] += a3 * b2; acc[3][3] += a3 * b3;
  }
  #pragma unroll
  for (int x = 0; x < 4; ++x)
    #pragma unroll
    for (int y = 0; y < 4; ++y)
      T2[(size_t)bh * 4096 + (ri + x) * 64 + ci + y] = acc[x][y];
}

// ---------------------------------------------------------------------------
// K10: conv residual -> d_out. Register sliding window: thread = (b,d,8 n's),
// all 8 out channels. Weights in LDS transposed to [i][t][o].
// ---------------------------------------------------------------------------
__global__ void __launch_bounds__(256) k_conv(const float* __restrict__ v,
                                              const float* __restrict__ cw,
                                              float* __restrict__ out) {
  __shared__ float wl[2112]; // [i][t][o] = i*264 + t*8 + o
  int tid = threadIdx.x;
  for (int idx = tid; idx < 2112; idx += 256) {
    int o = idx / 264, r = idx % 264, i = r / 33, t = r % 33;
    wl[i * 264 + t * 8 + o] = cw[idx];
  }
  __syncthreads();
  int d = tid & 63;
  int sub = tid >> 6;                         // 0..3
  int b = blockIdx.x >> 7;                    // 8 b
  int n0 = (blockIdx.x & 127) * 32 + sub * 8; // 8 outputs per thread
  float acc[8][8] = {};                       // [o][u]
  for (int i = 0; i < 8; ++i) {
    const float* vp = v + ((size_t)(b * 8 + i) * cN) * 64 + d;
    float win[40];
    #pragma unroll
    for (int t = 0; t < 40; ++t) {
      int nn = n0 - 16 + t;
      win[t] = (nn >= 0 && nn < cN) ? vp[(size_t)nn * 64] : 0.f;
    }
    #pragma unroll
    for (int t = 0; t < 33; ++t) {
      float4 w0 = *(const float4*)&wl[i * 264 + t * 8];
      float4 w1 = *(const float4*)&wl[i * 264 + t * 8 + 4];
      #pragma unroll
      for (int u = 0; u < 8; ++u) {
        float val = win[t + u];
        acc[0][u] += val * w0.x; acc[1][u] += val * w0.y;
        acc[2][u] += val * w0.z; acc[3][u] += val * w0.w;
        acc[4][u] += val * w1.x; acc[5][u] += val * w1.y;
        acc[6][u] += val * w1.z; acc[7][u] += val * w1.w;
      }
    }
  }
  #pragma unroll
  for (int o = 0; o < 8; ++o) {
    float* op = out + ((size_t)(b * 8 + o) * cN + n0) * 64 + d;
    #pragma unroll
    for (int u = 0; u < 8; ++u) op[(size_t)u * 64] = acc[o][u];
  }
}

// ---------------------------------------------------------------------------
// K11: fused sim1 chain, register-resident. Block per (b, 32-row i-tile).
// Thread: i = tid>>3, jb = (tid&7)*8; sim[8k][8j] in registers.
// Phase1: sim1 = q@kl^T, mix Wsim1. Softmax via 8-lane shuffles. Mix Wattn1.
// Phase2: per k2, P -> LDS, out += P @ T2[k2]  (on top of conv residual).
// ---------------------------------------------------------------------------
__global__ void __launch_bounds__(256) k_final(const float* __restrict__ q,
                                               const float* __restrict__ kl,
                                               const float* __restrict__ T2,
                                               const float* __restrict__ Wsim1,
                                               const float* __restrict__ Wattn1,
                                               float* __restrict__ out) {
  __shared__ float bufS[32 * 72];  // phase1: qs[i][d]; phase2: P[i][j]
  __shared__ float bufL[64 * 68];  // phase1: klT[d][j]; phase2: t2s[j][d]
  __shared__ float ws1[64], wa1[64];
  int b = blockIdx.x >> 7, it = blockIdx.x & 127, i0 = it * 32, tid = threadIdx.x;
  if (tid < 64) { ws1[tid] = Wsim1[tid]; wa1[tid] = Wattn1[tid]; }
  int i = tid >> 3, jb = (tid & 7) * 8;
  float sim[8][8] = {};   // [k][c]
  for (int h = 0; h < 8; ++h) {
    __syncthreads();
    const float* qg = q + ((size_t)(b * 8 + h) * cN + i0) * 64;
    for (int idx = tid; idx < 2048; idx += 256)
      bufS[(idx >> 6) * 72 + (idx & 63)] = qg[idx];
    const float* kg = kl + (size_t)(b * 8 + h) * 4096;
    for (int idx = tid; idx < 4096; idx += 256)
      bufL[(idx & 63) * 68 + (idx >> 6)] = kg[idx];  // transpose -> [d][j]
    __syncthreads();
    float s[8] = {};
    for (int d = 0; d < 64; ++d) {
      float a = bufS[i * 72 + d];
      float4 k0 = *(const float4*)&bufL[d * 68 + jb];
      float4 k1 = *(const float4*)&bufL[d * 68 + jb + 4];
      s[0] += a * k0.x; s[1] += a * k0.y; s[2] += a * k0.z; s[3] += a * k0.w;
      s[4] += a * k1.x; s[5] += a * k1.y; s[6] += a * k1.z; s[7] += a * k1.w;
    }
    #pragma unroll
    for (int k = 0; k < 8; ++k) {
      float wv = ws1[h * 8 + k];
      #pragma unroll
      for (int c = 0; c < 8; ++c) sim[k][c] += wv * s[c];
    }
  }
  // softmax over j=64: each row i lives on 8 consecutive lanes
  #pragma unroll
  for (int k = 0; k < 8; ++k) {
    float mx = sim[k][0];
    #pragma unroll
    for (int c = 1; c < 8; ++c) mx = fmaxf(mx, sim[k][c]);
    mx = fmaxf(mx, __shfl_xor(mx, 1));
    mx = fmaxf(mx, __shfl_xor(mx, 2));
    mx = fmaxf(mx, __shfl_xor(mx, 4));
    float sm = 0.f;
    #pragma unroll
    for (int c = 0; c < 8; ++c) { sim[k][c] = expf(sim[k][c] - mx); sm += sim[k][c]; }
    sm += __shfl_xor(sm, 1);
    sm += __shfl_xor(sm, 2);
    sm += __shfl_xor(sm, 4);
    float inv = 1.0f / sm;
    #pragma unroll
    for (int c = 0; c < 8; ++c) sim[k][c] *= inv;
  }
  // Wattn1 mix, in registers
  #pragma unroll
  for (int c = 0; c < 8; ++c) {
    float t[8];
    #pragma unroll
    for (int k2 = 0; k2 < 8; ++k2) {
      float acc = 0.f;
      #pragma unroll
      for (int k = 0; k < 8; ++k) acc += sim[k][c] * wa1[k * 8 + k2];
      t[k2] = acc;
    }
    #pragma unroll
    for (int k2 = 0; k2 < 8; ++k2) sim[k2][c] = t[k2];
  }
  // phase 2: per k2, out += P @ T2[k2]
  for (int k2 = 0; k2 < 8; ++k2) {
    __syncthreads();
    *(float4*)&bufS[i * 72 + jb] = make_float4(sim[k2][0], sim[k2][1], sim[k2][2], sim[k2][3]);
    *(float4*)&bufS[i * 72 + jb + 4] = make_float4(sim[k2][4], sim[k2][5], sim[k2][6], sim[k2][7]);
    const float* tg = T2 + (size_t)(b * 8 + k2) * 4096;
    for (int idx = tid; idx < 4096; idx += 256)
      bufL[(idx >> 6) * 68 + (idx & 63)] = tg[idx];
    __syncthreads();
    int db = jb;
    float o[8] = {};
    for (int j = 0; j < 64; ++j) {
      float p = bufS[i * 72 + j];
      float4 t0 = *(const float4*)&bufL[j * 68 + db];
      float4 t1 = *(const float4*)&bufL[j * 68 + db + 4];
      o[0] += p * t0.x; o[1] += p * t0.y; o[2] += p * t0.z; o[3] += p * t0.w;
      o[4] += p * t1.x; o[5] += p * t1.y; o[6] += p * t1.z; o[7] += p * t1.w;
    }
    float* op = out + ((size_t)(b * 8 + k2) * cN + i0 + i) * 64 + db;
    float4 e0 = *(float4*)op;
    float4 e1 = *(float4*)(op + 4);
    e0.x += o[0]; e0.y += o[1]; e0.z += o[2]; e0.w += o[3];
    e1.x += o[4]; e1.y += o[5]; e1.z += o[6]; e1.w += o[7];
    *(float4*)op = e0;
    *(float4*)(op + 4) = e1;
  }
}

// ---------------------------------------------------------------------------
extern "C" void kernel_launch(void* const* d_in, const int* in_sizes, int n_in,
                              void* d_out, int out_size, void* d_ws, size_t ws_size,
                              hipStream_t stream) {
  const float* q = (const float*)d_in[0];
  const float* k = (const float*)d_in[1];
  const float* v = (const float*)d_in[2];
  const float* Wsim1 = (const float*)d_in[3];
  const float* Wsim2 = (const float*)d_in[4];
  const float* Wsim3 = (const float*)d_in[5];
  const float* Wattn1 = (const float*)d_in[6];
  const float* Wattn2 = (const float*)d_in[7];
  const float* Wattn3 = (const float*)d_in[8];
  const float* cw = (const float*)d_in[9];
  float* out = (float*)d_out;
  float* ws = (float*)d_ws;

  float* ql       = ws + 0;
  float* kl       = ws + 262144;
  float* attn2    = ws + 524288;
  float* attn2inv = ws + 786432;
  float* attn2m   = ws + 1048576;
  float* T2       = ws + 1310720;
  float* rmax     = ws + 1572864;
  float* rsum     = ws + 1576960;
  unsigned int* scal = (unsigned int*)(ws + 1581056);
  float* T3p      = ws + 1581120;  // 4 * 64 * 4096 = 1,048,576 floats
  // d_out (exactly B*H*64*N floats) doubles as sim3m scratch; fully consumed
  // by k_t3 before k_conv overwrites d_out with the conv residual.
  float* sim3m = out;

  hipMemsetAsync(scal, 0, 8, stream);
  k_landmarks<<<dim3(4096), dim3(64), 0, stream>>>(q, k, ql, kl);
  k_sim2<<<dim3(64), dim3(256), 0, stream>>>(ql, kl, Wsim2, attn2, scal);
  k_pinv<<<dim3(64), dim3(256), 0, stream>>>(attn2, attn2inv, scal);
  k_mix_heads64<<<dim3(64), dim3(256), 0, stream>>>(attn2inv, Wattn2, attn2m);
  k_sim3<<<dim3(1024), dim3(256), 0, stream>>>(ql, k, Wsim3, sim3m);
  k_stats3<<<dim3(4096), dim3(256), 0, stream>>>(sim3m, rmax, rsum);
  k_smx3<<<dim3(8192), dim3(256), 0, stream>>>(sim3m, rmax, rsum, Wattn3);
  k_t3<<<dim3(256), dim3(256), 0, stream>>>(sim3m, v, T3p);
  k_t2<<<dim3(64), dim3(256), 0, stream>>>(attn2m, T3p, T2);
  k_conv<<<dim3(1024), dim3(256), 0, stream>>>(v, cw, out);
  k_final<<<dim3(1024), dim3(256), 0, stream>>>(q, kl, T2, Wsim1, Wattn1, out);
}

// Round 3
// 902.288 us; speedup vs baseline: 6.6171x; 6.6171x over previous
//
#include <hip/hip_runtime.h>
#include <cstddef>
#include <cstdint>

// Problem constants
constexpr int cB = 8, cH = 8, cN = 4096, cD = 64, cM = 64, cL = 64;

// ---------------------------------------------------------------------------
// K1: landmarks  q_l/k_l[bh][m][d] = mean over l=64 tokens
// ---------------------------------------------------------------------------
__global__ void k_landmarks(const float* __restrict__ q, const float* __restrict__ k,
                            float* __restrict__ ql, float* __restrict__ kl) {
  int bm = blockIdx.x;          // BH*M = 4096
  int bh = bm >> 6, m = bm & 63;
  int d = threadIdx.x;          // 64
  size_t base = ((size_t)bh * cN + (size_t)m * cL) * cD + d;
  float sq = 0.f, sk = 0.f;
  for (int t = 0; t < cL; ++t) {
    sq += q[base + (size_t)t * cD];
    sk += k[base + (size_t)t * cD];
  }
  size_t ob = ((size_t)bh * cM + m) * cD + d;
  ql[ob] = sq * (1.0f / cL);
  kl[ob] = sk * (1.0f / cL);
}

// ---------------------------------------------------------------------------
// K2: sim2 = q_l k_l^T, mix heads (Wsim2), softmax rows, write attn2.
// Also atomicMax of global col-sum max (scal[0]) and row-sum max (scal[1]).
// ---------------------------------------------------------------------------
__global__ void __launch_bounds__(256) k_sim2(const float* __restrict__ ql,
                                              const float* __restrict__ kl,
                                              const float* __restrict__ Wsim2,
                                              float* __restrict__ attn2,
                                              unsigned int* __restrict__ scal) {
  __shared__ float qs[64][65];
  __shared__ float ks[64][65];
  __shared__ float acc[64 * 65];
  int b = blockIdx.x >> 3, kk = blockIdx.x & 7;
  int tid = threadIdx.x;
  for (int idx = tid; idx < 64 * 64; idx += 256)
    acc[(idx >> 6) * 65 + (idx & 63)] = 0.f;
  int ri = (tid >> 4) * 4, ci = (tid & 15) * 4;
  for (int h = 0; h < 8; ++h) {
    __syncthreads();
    const float* qg = ql + (size_t)(b * 8 + h) * 4096;
    const float* kg = kl + (size_t)(b * 8 + h) * 4096;
    for (int idx = tid; idx < 4096; idx += 256) {
      qs[idx >> 6][idx & 63] = qg[idx];
      ks[idx >> 6][idx & 63] = kg[idx];
    }
    __syncthreads();
    float w = Wsim2[h * 8 + kk];
    float s[4][4] = {};
    for (int d = 0; d < 64; ++d) {
      float a0 = qs[ri][d], a1 = qs[ri + 1][d], a2 = qs[ri + 2][d], a3 = qs[ri + 3][d];
      float b0 = ks[ci][d], b1 = ks[ci + 1][d], b2 = ks[ci + 2][d], b3 = ks[ci + 3][d];
      s[0][0] += a0 * b0; s[0][1] += a0 * b1; s[0][2] += a0 * b2; s[0][3] += a0 * b3;
      s[1][0] += a1 * b0; s[1][1] += a1 * b1; s[1][2] += a1 * b2; s[1][3] += a1 * b3;
      s[2][0] += a2 * b0; s[2][1] += a2 * b1; s[2][2] += a2 * b2; s[2][3] += a2 * b3;
      s[3][0] += a3 * b0; s[3][1] += a3 * b1; s[3][2] += a3 * b2; s[3][3] += a3 * b3;
    }
    #pragma unroll
    for (int x = 0; x < 4; ++x)
      #pragma unroll
      for (int y = 0; y < 4; ++y)
        acc[(ri + x) * 65 + ci + y] += w * s[x][y];
  }
  __syncthreads();
  if (tid < 64) {
    float mx = -1e30f;
    for (int j = 0; j < 64; ++j) mx = fmaxf(mx, acc[tid * 65 + j]);
    float s = 0.f;
    for (int j = 0; j < 64; ++j) {
      float e = expf(acc[tid * 65 + j] - mx);
      acc[tid * 65 + j] = e;
      s += e;
    }
    float inv = 1.0f / s;
    float rs = 0.f;
    for (int j = 0; j < 64; ++j) {
      float p = acc[tid * 65 + j] * inv;
      acc[tid * 65 + j] = p;
      rs += p;
    }
    atomicMax(scal + 1, __float_as_uint(rs));
  }
  __syncthreads();
  if (tid < 64) {
    float cs = 0.f;
    for (int i = 0; i < 64; ++i) cs += acc[i * 65 + tid];
    atomicMax(scal + 0, __float_as_uint(cs));
  }
  __syncthreads();
  float* op = attn2 + (size_t)(b * 8 + kk) * 4096;
  for (int idx = tid; idx < 4096; idx += 256)
    op[idx] = acc[(idx >> 6) * 65 + (idx & 63)];
}

// ---------------------------------------------------------------------------
// K3: Moore-Penrose pinv, 6 Newton-Schulz iterations in LDS, per (b,k) block.
// ---------------------------------------------------------------------------
__device__ __forceinline__ void mm64(float* __restrict__ Dst, const float* S,
                                     float c0, float c1, const float* __restrict__ P,
                                     const float* __restrict__ Q, int tid) {
  int ri = (tid >> 4) * 4, ci = (tid & 15) * 4;
  float s[4][4] = {};
  for (int k = 0; k < 64; ++k) {
    float a0 = P[(ri + 0) * 65 + k], a1 = P[(ri + 1) * 65 + k];
    float a2 = P[(ri + 2) * 65 + k], a3 = P[(ri + 3) * 65 + k];
    float b0 = Q[k * 65 + ci + 0], b1 = Q[k * 65 + ci + 1];
    float b2 = Q[k * 65 + ci + 2], b3 = Q[k * 65 + ci + 3];
    s[0][0] += a0 * b0; s[0][1] += a0 * b1; s[0][2] += a0 * b2; s[0][3] += a0 * b3;
    s[1][0] += a1 * b0; s[1][1] += a1 * b1; s[1][2] += a1 * b2; s[1][3] += a1 * b3;
    s[2][0] += a2 * b0; s[2][1] += a2 * b1; s[2][2] += a2 * b2; s[2][3] += a2 * b3;
    s[3][0] += a3 * b0; s[3][1] += a3 * b1; s[3][2] += a3 * b2; s[3][3] += a3 * b3;
  }
  #pragma unroll
  for (int x = 0; x < 4; ++x)
    #pragma unroll
    for (int y = 0; y < 4; ++y) {
      float r = c1 * s[x][y];
      if (S) r += c0 * S[(ri + x) * 65 + ci + y];
      Dst[(ri + x) * 65 + ci + y] = r;
    }
}

__global__ void __launch_bounds__(256) k_pinv(const float* __restrict__ attn2,
                                              float* __restrict__ attn2inv,
                                              const unsigned int* __restrict__ scal) {
  __shared__ float bufs[5][64 * 65];
  float* X = bufs[0];
  float* Z = bufs[1];
  float* T1 = bufs[2];
  float* T2 = bufs[3];
  float* T3 = bufs[4];
  int tid = threadIdx.x;
  const float* xg = attn2 + (size_t)blockIdx.x * 4096;
  for (int idx = tid; idx < 4096; idx += 256)
    X[(idx >> 6) * 65 + (idx & 63)] = xg[idx];
  float denom = __uint_as_float(scal[0]) * __uint_as_float(scal[1]);
  float invd = 1.0f / denom;
  __syncthreads();
  for (int idx = tid; idx < 4096; idx += 256) {
    int i = idx >> 6, j = idx & 63;
    Z[i * 65 + j] = X[j * 65 + i] * invd;
  }
  __syncthreads();
  for (int it = 0; it < 6; ++it) {
    mm64(T1, nullptr, 0.f, 1.f, X, Z, tid);          __syncthreads();
    mm64(T2, T1, 7.f, -1.f, T1, T1, tid);            __syncthreads();
    mm64(T3, T1, 15.f, -1.f, T1, T2, tid);           __syncthreads();
    mm64(T2, Z, 13.f * 0.25f, -0.25f, Z, T3, tid);   __syncthreads();
    float* tmp = Z; Z = T2; T2 = tmp;
  }
  float* og = attn2inv + (size_t)blockIdx.x * 4096;
  for (int idx = tid; idx < 4096; idx += 256)
    og[idx] = Z[(idx >> 6) * 65 + (idx & 63)];
}

// ---------------------------------------------------------------------------
// K4: head-mix of 64x64 mats: out[b][k2] = sum_k in[b][k] * W[k][k2]
// ---------------------------------------------------------------------------
__global__ void k_mix_heads64(const float* __restrict__ in, const float* __restrict__ W,
                              float* __restrict__ out) {
  int b = blockIdx.x >> 3, k2 = blockIdx.x & 7;
  int tid = threadIdx.x;
  __shared__ float w[8];
  if (tid < 8) w[tid] = W[tid * 8 + k2];
  __syncthreads();
  const float* ib = in + (size_t)b * 8 * 4096;
  float* ob = out + ((size_t)b * 8 + k2) * 4096;
  for (int idx = tid; idx < 4096; idx += 256) {
    float s = 0.f;
    #pragma unroll
    for (int k = 0; k < 8; ++k) s += ib[(size_t)k * 4096 + idx] * w[k];
    ob[idx] = s;
  }
}

// ---------------------------------------------------------------------------
// K5: sim3m[b][k][i][j] = sum_h Wsim3[h][k]*(q_l[b,h,i,:].k[b,h,j,:])
// 512 threads: i = tid>>3 (0..63), jb = (tid&7)*4. acc[8][4] = 32 regs
// (R2's acc[8][8]=64 spilled at VGPR cap 256 -> 0.8% VALUBusy).
// ---------------------------------------------------------------------------
__global__ void __launch_bounds__(512) k_sim3(const float* __restrict__ ql,
                                              const float* __restrict__ kg,
                                              const float* __restrict__ Wsim3,
                                              float* __restrict__ sim3m) {
  __shared__ float qls[64 * 65];   // [i][d] pitch 65
  __shared__ float ksT[64 * 36];   // [d][j] pitch 36 (16B-aligned float4 rows)
  __shared__ float w3[64];
  int b = blockIdx.x >> 7, jt = blockIdx.x & 127;
  int j0 = jt * 32, tid = threadIdx.x;
  if (tid < 64) w3[tid] = Wsim3[tid];
  int i = tid >> 3, jb = (tid & 7) * 4;
  float acc[8][4] = {};
  for (int h = 0; h < 8; ++h) {
    __syncthreads();
    const float* qg = ql + (size_t)(b * 8 + h) * 4096;
    for (int idx = tid; idx < 4096; idx += 512)
      qls[(idx >> 6) * 65 + (idx & 63)] = qg[idx];
    const float* kp = kg + ((size_t)(b * 8 + h) * cN + j0) * 64;
    for (int idx = tid; idx < 2048; idx += 512) {
      int j = idx >> 6, d = idx & 63;
      ksT[d * 36 + j] = kp[idx];
    }
    __syncthreads();
    float s[4] = {};
    for (int d = 0; d < 64; ++d) {
      float a = qls[i * 65 + d];
      float4 kv = *(const float4*)&ksT[d * 36 + jb];
      s[0] += a * kv.x; s[1] += a * kv.y; s[2] += a * kv.z; s[3] += a * kv.w;
    }
    #pragma unroll
    for (int k = 0; k < 8; ++k) {
      float w = w3[h * 8 + k];
      #pragma unroll
      for (int c = 0; c < 4; ++c) acc[k][c] += w * s[c];
    }
  }
  #pragma unroll
  for (int k = 0; k < 8; ++k) {
    float* op = sim3m + ((size_t)((b * 8 + k) * 64 + i)) * cN + j0 + jb;
    *(float4*)op = make_float4(acc[k][0], acc[k][1], acc[k][2], acc[k][3]);
  }
}

// ---------------------------------------------------------------------------
// K6: row stats for softmax over j=4096: one block per (b,k,i) row.
// ---------------------------------------------------------------------------
__global__ void k_stats3(const float* __restrict__ sim3m, float* __restrict__ rmax,
                         float* __restrict__ rsum) {
  int row = blockIdx.x; // 4096
  const float* rp = sim3m + (size_t)row * cN;
  int tid = threadIdx.x;
  float vv[16];
  float mx = -1e30f;
  #pragma unroll
  for (int t = 0; t < 16; ++t) {
    vv[t] = rp[tid + t * 256];
    mx = fmaxf(mx, vv[t]);
  }
  __shared__ float red[8];
  for (int off = 32; off > 0; off >>= 1) mx = fmaxf(mx, __shfl_down(mx, off));
  if ((tid & 63) == 0) red[tid >> 6] = mx;
  __syncthreads();
  mx = fmaxf(fmaxf(red[0], red[1]), fmaxf(red[2], red[3]));
  float s = 0.f;
  #pragma unroll
  for (int t = 0; t < 16; ++t) s += expf(vv[t] - mx);
  for (int off = 32; off > 0; off >>= 1) s += __shfl_down(s, off);
  __syncthreads();
  if ((tid & 63) == 0) red[4 + (tid >> 6)] = s;
  __syncthreads();
  if (tid == 0) {
    rmax[row] = mx;
    rsum[row] = red[4] + red[5] + red[6] + red[7];
  }
}

// ---------------------------------------------------------------------------
// K7: in-place softmax + Wattn3 head-mix on sim3m, register-resident.
// One thread per (b,i,j); 8 k-values in registers. 8192 blocks x 256.
// ---------------------------------------------------------------------------
__global__ void __launch_bounds__(256) k_smx3(float* __restrict__ sim3m,
                                              const float* __restrict__ rmax,
                                              const float* __restrict__ rsum,
                                              const float* __restrict__ Wattn3) {
  __shared__ float w[64];
  int tid = threadIdx.x;
  if (tid < 64) w[tid] = Wattn3[tid];
  __syncthreads();
  int gid = blockIdx.x * 256 + tid;   // 2^21 = 8b * 64i * 4096j
  int j = gid & 4095;
  int i = (gid >> 12) & 63;
  int b = gid >> 18;
  float p[8];
  #pragma unroll
  for (int k = 0; k < 8; ++k) {
    int row = (b * 8 + k) * 64 + i;
    p[k] = expf(sim3m[(size_t)row * cN + j] - rmax[row]) / rsum[row];
  }
  #pragma unroll
  for (int k2 = 0; k2 < 8; ++k2) {
    float t = 0.f;
    #pragma unroll
    for (int k = 0; k < 8; ++k) t += p[k] * w[k * 8 + k2];
    int row = (b * 8 + k2) * 64 + i;
    sim3m[(size_t)row * cN + j] = t;
  }
}

// ---------------------------------------------------------------------------
// K8: T3 partials: T3p[c][bh] = attn3f[bh][:, cchunk] @ v[bh][cchunk, :]
// 4 j-chunks of 1024 -> 256 blocks (one per CU).
// ---------------------------------------------------------------------------
__global__ void __launch_bounds__(256) k_t3(const float* __restrict__ attn3f,
                                            const float* __restrict__ v,
                                            float* __restrict__ T3p) {
  __shared__ float As[64][65];
  __shared__ float Vs[64][68];
  int bh = blockIdx.x >> 2, chunk = blockIdx.x & 3;
  int tid = threadIdx.x;
  int ri = (tid >> 4) * 4, ci = (tid & 15) * 4;
  float acc[4][4] = {};
  for (int jt = chunk * 16; jt < chunk * 16 + 16; ++jt) {
    __syncthreads();
    const float* ap = attn3f + (size_t)bh * 64 * cN + jt * 64;
    for (int idx = tid; idx < 4096; idx += 256)
      As[idx >> 6][idx & 63] = ap[(size_t)(idx >> 6) * cN + (idx & 63)];
    const float* vp = v + ((size_t)bh * cN + jt * 64) * 64;
    for (int idx = tid; idx < 4096; idx += 256)
      Vs[idx >> 6][idx & 63] = vp[idx];
    __syncthreads();
    for (int j = 0; j < 64; ++j) {
      float a0 = As[ri][j], a1 = As[ri + 1][j], a2 = As[ri + 2][j], a3 = As[ri + 3][j];
      float b0 = Vs[j][ci], b1 = Vs[j][ci + 1], b2 = Vs[j][ci + 2], b3 = Vs[j][ci + 3];
      acc[0][0] += a0 * b0; acc[0][1] += a0 * b1; acc[0][2] += a0 * b2; acc[0][3] += a0 * b3;
      acc[1][0] += a1 * b0; acc[1][1] += a1 * b1; acc[1][2] += a1 * b2; acc[1][3] += a1 * b3;
      acc[2][0] += a2 * b0; acc[2][1] += a2 * b1; acc[2][2] += a2 * b2; acc[2][3] += a2 * b3;
      acc[3][0] += a3 * b0; acc[3][1] += a3 * b1; acc[3][2] += a3 * b2; acc[3][3] += a3 * b3;
    }
  }
  float* op = T3p + ((size_t)chunk * 64 + bh) * 4096;
  #pragma unroll
  for (int x = 0; x < 4; ++x)
    #pragma unroll
    for (int y = 0; y < 4; ++y)
      op[(ri + x) * 64 + ci + y] = acc[x][y];
}

// ---------------------------------------------------------------------------
// K9: T2[bh] = attn2m[bh] @ (sum of 4 T3 partials). Block per bh.
// ---------------------------------------------------------------------------
__global__ void __launch_bounds__(256) k_t2(const float* __restrict__ attn2m,
                                            const float* __restrict__ T3p,
                                            float* __restrict__ T2) {
  __shared__ float As[64][65];
  __shared__ float Bs[64][68];
  int bh = blockIdx.x, tid = threadIdx.x;
  const float* ap = attn2m + (size_t)bh * 4096;
  for (int idx = tid; idx < 4096; idx += 256) {
    As[idx >> 6][idx & 63] = ap[idx];
    float s = 0.f;
    #pragma unroll
    for (int c = 0; c < 4; ++c) s += T3p[((size_t)c * 64 + bh) * 4096 + idx];
    Bs[idx >> 6][idx & 63] = s;
  }
  __syncthreads();
  int ri = (tid >> 4) * 4, ci = (tid & 15) * 4;
  float acc[4][4] = {};
  for (int j = 0; j < 64; ++j) {
    float a0 = As[ri][j], a1 = As[ri + 1][j], a2 = As[ri + 2][j], a3 = As[ri + 3][j];
    float b0 = Bs[j][ci], b1 = Bs[j][ci + 1], b2 = Bs[j][ci + 2], b3 = Bs[j][ci + 3];
    acc[0][0] += a0 * b0; acc[0][1] += a0 * b1; acc[0][2] += a0 * b2; acc[0][3] += a0 * b3;
    acc[1][0] += a1 * b0; acc[1][1] += a1 * b1; acc[1][2] += a1 * b2; acc[1][3] += a1 * b3;
    acc[2][0] += a2 * b0; acc[2][1] += a2 * b1; acc[2][2] += a2 * b2; acc[2][3] += a2 * b3;
    acc[3][0] += a3 * b0; acc[3][1] += a3 * b1; acc[3][2] += a3 * b2; acc[3][3] += a3 * b3;
  }
  #pragma unroll
  for (int x = 0; x < 4; ++x)
    #pragma unroll
    for (int y = 0; y < 4; ++y)
      T2[(size_t)bh * 4096 + (ri + x) * 64 + ci + y] = acc[x][y];
}

// ---------------------------------------------------------------------------
// K10: conv residual -> d_out. Register sliding window: thread = (b,d,4 n's),
// all 8 out channels; acc[8][4]+win[36] (~85 VGPR, below spill line).
// ---------------------------------------------------------------------------
__global__ void __launch_bounds__(256) k_conv(const float* __restrict__ v,
                                              const float* __restrict__ cw,
                                              float* __restrict__ out) {
  __shared__ float wl[2112]; // [i][t][o] = i*264 + t*8 + o
  int tid = threadIdx.x;
  for (int idx = tid; idx < 2112; idx += 256) {
    int o = idx / 264, r = idx % 264, i = r / 33, t = r % 33;
    wl[i * 264 + t * 8 + o] = cw[idx];
  }
  __syncthreads();
  int d = tid & 63;
  int sub = tid >> 6;                        // 0..3
  int b = blockIdx.x >> 8;                   // 8 b
  int n0 = (blockIdx.x & 255) * 16 + sub * 4;
  float acc[8][4] = {};                      // [o][u]
  for (int i = 0; i < 8; ++i) {
    const float* vp = v + ((size_t)(b * 8 + i) * cN) * 64 + d;
    float win[36];
    #pragma unroll
    for (int t = 0; t < 36; ++t) {
      int nn = n0 - 16 + t;
      win[t] = (nn >= 0 && nn < cN) ? vp[(size_t)nn * 64] : 0.f;
    }
    #pragma unroll
    for (int t = 0; t < 33; ++t) {
      float4 w0 = *(const float4*)&wl[i * 264 + t * 8];
      float4 w1 = *(const float4*)&wl[i * 264 + t * 8 + 4];
      #pragma unroll
      for (int u = 0; u < 4; ++u) {
        float val = win[t + u];
        acc[0][u] += val * w0.x; acc[1][u] += val * w0.y;
        acc[2][u] += val * w0.z; acc[3][u] += val * w0.w;
        acc[4][u] += val * w1.x; acc[5][u] += val * w1.y;
        acc[6][u] += val * w1.z; acc[7][u] += val * w1.w;
      }
    }
  }
  #pragma unroll
  for (int o = 0; o < 8; ++o) {
    float* op = out + ((size_t)(b * 8 + o) * cN + n0) * 64 + d;
    #pragma unroll
    for (int u = 0; u < 4; ++u) op[(size_t)u * 64] = acc[o][u];
  }
}

// ---------------------------------------------------------------------------
// K11: fused sim1 chain, 512 threads, sim[8][4] per thread (no spills).
// Thread: i = tid>>4 (0..31), jb = (tid&15)*4. Block per (b, 32-row i-tile).
// Phase1: sim1 = q@kl^T, mix Wsim1. Softmax over 16 lanes. Mix Wattn1.
// Phase2: per k2, P -> LDS, out += P @ T2[k2]  (on top of conv residual).
// ---------------------------------------------------------------------------
__global__ void __launch_bounds__(512) k_final(const float* __restrict__ q,
                                               const float* __restrict__ kl,
                                               const float* __restrict__ T2,
                                               const float* __restrict__ Wsim1,
                                               const float* __restrict__ Wattn1,
                                               float* __restrict__ out) {
  __shared__ float bufS[32 * 68];  // phase1: qs[i][d]; phase2: P[i][j]
  __shared__ float bufL[64 * 68];  // phase1: klT[d][j]; phase2: t2s[j][d]
  __shared__ float ws1[64], wa1[64];
  int b = blockIdx.x >> 7, it = blockIdx.x & 127, i0 = it * 32, tid = threadIdx.x;
  if (tid < 64) { ws1[tid] = Wsim1[tid]; wa1[tid] = Wattn1[tid]; }
  int i = tid >> 4, jb = (tid & 15) * 4;
  float sim[8][4] = {};   // [k][c]
  for (int h = 0; h < 8; ++h) {
    __syncthreads();
    const float* qg = q + ((size_t)(b * 8 + h) * cN + i0) * 64;
    for (int idx = tid; idx < 2048; idx += 512)
      bufS[(idx >> 6) * 68 + (idx & 63)] = qg[idx];
    const float* kg = kl + (size_t)(b * 8 + h) * 4096;
    for (int idx = tid; idx < 4096; idx += 512)
      bufL[(idx & 63) * 68 + (idx >> 6)] = kg[idx];  // transpose -> [d][j]
    __syncthreads();
    float s[4] = {};
    for (int d = 0; d < 64; ++d) {
      float a = bufS[i * 68 + d];
      float4 kv = *(const float4*)&bufL[d * 68 + jb];
      s[0] += a * kv.x; s[1] += a * kv.y; s[2] += a * kv.z; s[3] += a * kv.w;
    }
    #pragma unroll
    for (int k = 0; k < 8; ++k) {
      float wv = ws1[h * 8 + k];
      #pragma unroll
      for (int c = 0; c < 4; ++c) sim[k][c] += wv * s[c];
    }
  }
  // softmax over j=64: each row i lives on 16 consecutive lanes
  #pragma unroll
  for (int k = 0; k < 8; ++k) {
    float mx = sim[k][0];
    #pragma unroll
    for (int c = 1; c < 4; ++c) mx = fmaxf(mx, sim[k][c]);
    mx = fmaxf(mx, __shfl_xor(mx, 1));
    mx = fmaxf(mx, __shfl_xor(mx, 2));
    mx = fmaxf(mx, __shfl_xor(mx, 4));
    mx = fmaxf(mx, __shfl_xor(mx, 8));
    float sm = 0.f;
    #pragma unroll
    for (int c = 0; c < 4; ++c) { sim[k][c] = expf(sim[k][c] - mx); sm += sim[k][c]; }
    sm += __shfl_xor(sm, 1);
    sm += __shfl_xor(sm, 2);
    sm += __shfl_xor(sm, 4);
    sm += __shfl_xor(sm, 8);
    float inv = 1.0f / sm;
    #pragma unroll
    for (int c = 0; c < 4; ++c) sim[k][c] *= inv;
  }
  // Wattn1 mix, in registers
  #pragma unroll
  for (int c = 0; c < 4; ++c) {
    float t[8];
    #pragma unroll
    for (int k2 = 0; k2 < 8; ++k2) {
      float acc = 0.f;
      #pragma unroll
      for (int k = 0; k < 8; ++k) acc += sim[k][c] * wa1[k * 8 + k2];
      t[k2] = acc;
    }
    #pragma unroll
    for (int k2 = 0; k2 < 8; ++k2) sim[k2][c] = t[k2];
  }
  // phase 2: per k2, out += P @ T2[k2]
  for (int k2 = 0; k2 < 8; ++k2) {
    __syncthreads();
    *(float4*)&bufS[i * 68 + jb] =
        make_float4(sim[k2][0], sim[k2][1], sim[k2][2], sim[k2][3]);
    const float* tg = T2 + (size_t)(b * 8 + k2) * 4096;
    for (int idx = tid; idx < 4096; idx += 512)
      bufL[(idx >> 6) * 68 + (idx & 63)] = tg[idx];
    __syncthreads();
    int db = jb;
    float o[4] = {};
    for (int j = 0; j < 64; ++j) {
      float p = bufS[i * 68 + j];
      float4 t = *(const float4*)&bufL[j * 68 + db];
      o[0] += p * t.x; o[1] += p * t.y; o[2] += p * t.z; o[3] += p * t.w;
    }
    float* op = out + ((size_t)(b * 8 + k2) * cN + i0 + i) * 64 + db;
    float4 e = *(float4*)op;
    e.x += o[0]; e.y += o[1]; e.z += o[2]; e.w += o[3];
    *(float4*)op = e;
  }
}

// ---------------------------------------------------------------------------
extern "C" void kernel_launch(void* const* d_in, const int* in_sizes, int n_in,
                              void* d_out, int out_size, void* d_ws, size_t ws_size,
                              hipStream_t stream) {
  const float* q = (const float*)d_in[0];
  const float* k = (const float*)d_in[1];
  const float* v = (const float*)d_in[2];
  const float* Wsim1 = (const float*)d_in[3];
  const float* Wsim2 = (const float*)d_in[4];
  const float* Wsim3 = (const float*)d_in[5];
  const float* Wattn1 = (const float*)d_in[6];
  const float* Wattn2 = (const float*)d_in[7];
  const float* Wattn3 = (const float*)d_in[8];
  const float* cw = (const float*)d_in[9];
  float* out = (float*)d_out;
  float* ws = (float*)d_ws;

  float* ql       = ws + 0;
  float* kl       = ws + 262144;
  float* attn2    = ws + 524288;
  float* attn2inv = ws + 786432;
  float* attn2m   = ws + 1048576;
  float* T2       = ws + 1310720;
  float* rmax     = ws + 1572864;
  float* rsum     = ws + 1576960;
  unsigned int* scal = (unsigned int*)(ws + 1581056);
  float* T3p      = ws + 1581120;  // 4 * 64 * 4096 = 1,048,576 floats
  // d_out (exactly B*H*64*N floats) doubles as sim3m scratch; fully consumed
  // by k_t3 before k_conv overwrites d_out with the conv residual.
  float* sim3m = out;

  hipMemsetAsync(scal, 0, 8, stream);
  k_landmarks<<<dim3(4096), dim3(64), 0, stream>>>(q, k, ql, kl);
  k_sim2<<<dim3(64), dim3(256), 0, stream>>>(ql, kl, Wsim2, attn2, scal);
  k_pinv<<<dim3(64), dim3(256), 0, stream>>>(attn2, attn2inv, scal);
  k_mix_heads64<<<dim3(64), dim3(256), 0, stream>>>(attn2inv, Wattn2, attn2m);
  k_sim3<<<dim3(1024), dim3(512), 0, stream>>>(ql, k, Wsim3, sim3m);
  k_stats3<<<dim3(4096), dim3(256), 0, stream>>>(sim3m, rmax, rsum);
  k_smx3<<<dim3(8192), dim3(256), 0, stream>>>(sim3m, rmax, rsum, Wattn3);
  k_t3<<<dim3(256), dim3(256), 0, stream>>>(sim3m, v, T3p);
  k_t2<<<dim3(64), dim3(256), 0, stream>>>(attn2m, T3p, T2);
  k_conv<<<dim3(2048), dim3(256), 0, stream>>>(v, cw, out);
  k_final<<<dim3(1024), dim3(512), 0, stream>>>(q, kl, T2, Wsim1, Wattn1, out);
}